// Round 4
// baseline (235.084 us; speedup 1.0000x reference)
//
#include <hip/hip_runtime.h>
#include <math.h>

#define Bb 2
#define Tt 256
#define Ee 512
#define Hh 8
#define Dd 64
#define E3 1536

typedef float vfloat4 __attribute__((ext_vector_type(4)));

__device__ inline float4 ntload4(const float* p) {
    vfloat4 v = __builtin_nontemporal_load((const vfloat4*)p);
    return make_float4(v.x, v.y, v.z, v.w);
}

// LDS-free GEMM: C[M][N] = A[M][K] @ W[K][N] + bias[N].
// Tile (RPT*16) x 64, 256 threads, RPT x 4 outputs/thread. A-frags are
// 16-lane-broadcast L1 hits (16 row-lines/wave live); B row-slices (256B)
// are shared by all waves -> L1-hot. No LDS, no barriers; VALU-bound.
template<int RPT>
__global__ __launch_bounds__(256) void gemm_bias_nolds(
    const float* __restrict__ A, const float* __restrict__ W,
    const float* __restrict__ bias, float* __restrict__ C,
    int M, int N, int K)
{
    const int tid = threadIdx.x;
    const int tx = tid & 15;            // col group: n0 + tx*4 .. +3
    const int ty = tid >> 4;            // row group: m0 + ty*RPT .. +RPT-1
    const int n0 = blockIdx.x * 64;
    const int m0 = blockIdx.y * (RPT * 16);

    const float* wp = W + n0 + tx * 4;
    const float* ap = A + (size_t)(m0 + ty * RPT) * K;

    float acc[RPT][4];
    #pragma unroll
    for (int r = 0; r < RPT; ++r)
        #pragma unroll
        for (int j = 0; j < 4; ++j) acc[r][j] = 0.f;

    #pragma unroll 4
    for (int k = 0; k < K; k += 4) {
        float4 b[4];
        #pragma unroll
        for (int kk = 0; kk < 4; ++kk)
            b[kk] = *(const float4*)&wp[(size_t)(k + kk) * N];
        #pragma unroll
        for (int r = 0; r < RPT; ++r) {
            const float4 a4 = *(const float4*)&ap[(size_t)r * K + k];
            acc[r][0] = fmaf(a4.x, b[0].x, acc[r][0]);
            acc[r][1] = fmaf(a4.x, b[0].y, acc[r][1]);
            acc[r][2] = fmaf(a4.x, b[0].z, acc[r][2]);
            acc[r][3] = fmaf(a4.x, b[0].w, acc[r][3]);
            acc[r][0] = fmaf(a4.y, b[1].x, acc[r][0]);
            acc[r][1] = fmaf(a4.y, b[1].y, acc[r][1]);
            acc[r][2] = fmaf(a4.y, b[1].z, acc[r][2]);
            acc[r][3] = fmaf(a4.y, b[1].w, acc[r][3]);
            acc[r][0] = fmaf(a4.z, b[2].x, acc[r][0]);
            acc[r][1] = fmaf(a4.z, b[2].y, acc[r][1]);
            acc[r][2] = fmaf(a4.z, b[2].z, acc[r][2]);
            acc[r][3] = fmaf(a4.z, b[2].w, acc[r][3]);
            acc[r][0] = fmaf(a4.w, b[3].x, acc[r][0]);
            acc[r][1] = fmaf(a4.w, b[3].y, acc[r][1]);
            acc[r][2] = fmaf(a4.w, b[3].z, acc[r][2]);
            acc[r][3] = fmaf(a4.w, b[3].w, acc[r][3]);
        }
    }
    const float4 bs4 = *(const float4*)&bias[n0 + tx * 4];
    #pragma unroll
    for (int r = 0; r < RPT; ++r) {
        float4 o;
        o.x = acc[r][0] + bs4.x;
        o.y = acc[r][1] + bs4.y;
        o.z = acc[r][2] + bs4.z;
        o.w = acc[r][3] + bs4.w;
        *(float4*)&C[(size_t)(m0 + ty * RPT + r) * N + n0 + tx * 4] = o;
    }
}

// Block = (b, t-pair). 512 threads / 8 waves. Lane = (si in 8 s-rows, dq in 8 d-octets).
__global__ __launch_bounds__(512, 2) void attn_kernel(
    const float* __restrict__ qkv,     // (B*T, 1536): [q|k|v]
    const float* __restrict__ mask,    // (B, T, T, 32, 2) = (..., 64 floats)
    const float* __restrict__ pad,     // (B, T)
    float* __restrict__ o_attn,        // (B*T, 512)
    float* __restrict__ attn_w)        // (B*T, 256)
{
    __shared__ float q_s[2][Ee];       // 4 KB
    __shared__ float sc[2][Hh][Tt];    // 16 KB
    __shared__ float rrs[16];          // reciprocal softmax sums, row = tt*8+h
    const int tid  = threadIdx.x;
    const int lane = tid & 63;
    const int wv   = tid >> 6;         // 0..7
    const int si   = lane >> 3;        // 0..7
    const int dq   = lane & 7;         // 0..7 -> d = dq*8..dq*8+7
    const int b    = blockIdx.x >> 7;
    const int t0   = (blockIdx.x & 127) * 2;

    // stage q rows (t0, t0+1) into LDS: 1024 floats, float2 per thread
    {
        const int e = tid * 2;
        const int t = e >> 9, off = e & 511;
        *(float2*)&q_s[t][off] =
            *(const float2*)&qkv[(size_t)(b * Tt + t0 + t) * E3 + off];
    }
    __syncthreads();

    const float scale = 0.125f;  // 1/sqrt(64)

    // ---- scores: wave handles 4 chunks of 8 s-rows ----
    for (int c = 0; c < 4; ++c) {
        const int s = (wv * 4 + c) * 8 + si;
        const float* mrow0 = mask + ((size_t)((b * Tt + t0) * Tt + s)) * Dd + dq * 8;
        const float* mrow1 = mrow0 + (size_t)Tt * Dd;
        const float4 ma0 = ntload4(mrow0);
        const float4 mb0 = ntload4(mrow0 + 4);
        const float4 ma1 = ntload4(mrow1);
        const float4 mb1 = ntload4(mrow1 + 4);
        const float* krow = qkv + (size_t)(b * Tt + s) * E3 + Ee + dq * 8;
        const float padv = pad[b * Tt + s];
        #pragma unroll
        for (int h = 0; h < Hh; ++h) {
            const float4 ka = *(const float4*)(krow + h * 64);
            const float4 kb = *(const float4*)(krow + h * 64 + 4);
            const float4 qa0 = *(const float4*)&q_s[0][h * 64 + dq * 8];
            const float4 qb0 = *(const float4*)&q_s[0][h * 64 + dq * 8 + 4];
            const float4 qa1 = *(const float4*)&q_s[1][h * 64 + dq * 8];
            const float4 qb1 = *(const float4*)&q_s[1][h * 64 + dq * 8 + 4];
            // t0
            float u0 = qa0.x * ka.x + qa0.y * ka.y;
            float w0 = qa0.y * ka.x - qa0.x * ka.y;
            float u1 = qa0.z * ka.z + qa0.w * ka.w;
            float w1 = qa0.w * ka.z - qa0.z * ka.w;
            float u2 = qb0.x * kb.x + qb0.y * kb.y;
            float w2 = qb0.y * kb.x - qb0.x * kb.y;
            float u3 = qb0.z * kb.z + qb0.w * kb.w;
            float w3 = qb0.w * kb.z - qb0.z * kb.w;
            float v0 = u0 * ma0.x + w0 * ma0.y + u1 * ma0.z + w1 * ma0.w
                     + u2 * mb0.x + w2 * mb0.y + u3 * mb0.z + w3 * mb0.w;
            // t1
            float s0 = qa1.x * ka.x + qa1.y * ka.y;
            float r0 = qa1.y * ka.x - qa1.x * ka.y;
            float s1 = qa1.z * ka.z + qa1.w * ka.w;
            float r1 = qa1.w * ka.z - qa1.z * ka.w;
            float s2 = qb1.x * kb.x + qb1.y * kb.y;
            float r2 = qb1.y * kb.x - qb1.x * kb.y;
            float s3 = qb1.z * kb.z + qb1.w * kb.w;
            float r3 = qb1.w * kb.z - qb1.z * kb.w;
            float v1 = s0 * ma1.x + r0 * ma1.y + s1 * ma1.z + r1 * ma1.w
                     + s2 * mb1.x + r2 * mb1.y + s3 * mb1.z + r3 * mb1.w;
            // reduce over dq (8 lanes)
            v0 += __shfl_xor(v0, 1); v0 += __shfl_xor(v0, 2); v0 += __shfl_xor(v0, 4);
            v1 += __shfl_xor(v1, 1); v1 += __shfl_xor(v1, 2); v1 += __shfl_xor(v1, 4);
            if (dq == 0) {
                sc[0][h][s] = v0 * scale + padv;
                sc[1][h][s] = v1 * scale + padv;
            }
        }
    }
    __syncthreads();

    // ---- softmax: 16 rows (t,h); wave handles rows wv*2, wv*2+1 ----
    #pragma unroll
    for (int r = 0; r < 2; ++r) {
        const int row = wv * 2 + r;
        float* pr = &sc[0][0][0] + row * Tt;
        float4 xv = *(const float4*)&pr[lane * 4];
        float mx = fmaxf(fmaxf(xv.x, xv.y), fmaxf(xv.z, xv.w));
        #pragma unroll
        for (int dlt = 32; dlt >= 1; dlt >>= 1) mx = fmaxf(mx, __shfl_xor(mx, dlt));
        float4 ev;
        ev.x = __expf(xv.x - mx);
        ev.y = __expf(xv.y - mx);
        ev.z = __expf(xv.z - mx);
        ev.w = __expf(xv.w - mx);
        float sum = (ev.x + ev.y) + (ev.z + ev.w);
        #pragma unroll
        for (int dlt = 32; dlt >= 1; dlt >>= 1) sum += __shfl_xor(sum, dlt);
        *(float4*)&pr[lane * 4] = ev;
        if (lane == 0) rrs[row] = 1.0f / sum;
    }
    __syncthreads();

    // ---- attn_weights: thread (tt, s2) ----
    {
        const int tt = tid >> 8, s2 = tid & 255;
        float aw = 0.f;
        #pragma unroll
        for (int h = 0; h < Hh; ++h) aw += sc[tt][h][s2] * rrs[tt * 8 + h];
        attn_w[(size_t)(b * Tt + t0 + tt) * Tt + s2] = aw * 0.125f;
    }

    // ---- PV: thread (h, d), both t rows share v loads ----
    {
        const int h = tid >> 6, d = tid & 63;
        const float r0 = rrs[h], r1 = rrs[8 + h];
        const float* vb = qkv + (size_t)b * Tt * E3 + 2 * Ee + h * 64 + d;
        float o0 = 0.f, o1 = 0.f;
        for (int s2 = 0; s2 < Tt; s2 += 4) {
            const float4 p0 = *(const float4*)&sc[0][h][s2];
            const float4 p1 = *(const float4*)&sc[1][h][s2];
            float vv;
            vv = vb[(size_t)(s2 + 0) * E3]; o0 = fmaf(p0.x, vv, o0); o1 = fmaf(p1.x, vv, o1);
            vv = vb[(size_t)(s2 + 1) * E3]; o0 = fmaf(p0.y, vv, o0); o1 = fmaf(p1.y, vv, o1);
            vv = vb[(size_t)(s2 + 2) * E3]; o0 = fmaf(p0.z, vv, o0); o1 = fmaf(p1.z, vv, o1);
            vv = vb[(size_t)(s2 + 3) * E3]; o0 = fmaf(p0.w, vv, o0); o1 = fmaf(p1.w, vv, o1);
        }
        o_attn[(size_t)(b * Tt + t0) * Ee + tid]     = o0 * r0;
        o_attn[(size_t)(b * Tt + t0 + 1) * Ee + tid] = o1 * r1;
    }
}

extern "C" void kernel_launch(void* const* d_in, const int* in_sizes, int n_in,
                              void* d_out, int out_size, void* d_ws, size_t ws_size,
                              hipStream_t stream) {
    const float* x    = (const float*)d_in[0];
    const float* mask = (const float*)d_in[1];
    const float* pad  = (const float*)d_in[2];
    const float* Wqkv = (const float*)d_in[3];
    const float* bqkv = (const float*)d_in[4];
    const float* Wo   = (const float*)d_in[5];
    const float* bo   = (const float*)d_in[6];

    float* out    = (float*)d_out;               // o (B*T*E) then attn_w (B*T*T)
    float* qkv    = (float*)d_ws;                // B*T*3E = 786432 floats
    float* o_attn = qkv + (size_t)Bb * Tt * E3;  // B*T*E  = 262144 floats

    // qkv = x @ Wqkv + bqkv   (64x64 tiles: grid 24 x 8 = 192 blocks)
    gemm_bias_nolds<4><<<dim3(E3 / 64, (Bb * Tt) / 64), 256, 0, stream>>>(
        x, Wqkv, bqkv, qkv, Bb * Tt, E3, Ee);

    // fused rotary scores + softmax + attn_weights + PV  (256 blocks x 512 thr)
    attn_kernel<<<dim3(Bb * (Tt / 2)), 512, 0, stream>>>(
        qkv, mask, pad, o_attn, out + (size_t)Bb * Tt * Ee);

    // out = o_attn @ Wo + bo  (32x64 tiles: grid 8 x 16 = 128 blocks)
    gemm_bias_nolds<2><<<dim3(Ee / 64, (Bb * Tt) / 32), 256, 0, stream>>>(
        o_attn, Wo, bo, out, Bb * Tt, Ee, Ee);
}

// Round 5
// 70.562 us; speedup vs baseline: 3.3316x; 3.3316x over previous
//
#include <hip/hip_runtime.h>
#include <math.h>

#define Bb 2
#define Tt 256
#define Ee 512
#define Hh 8
#define Dd 64
#define E3 1536

typedef float vfloat4 __attribute__((ext_vector_type(4)));

__device__ inline float4 ntload4(const float* p) {
    vfloat4 v = __builtin_nontemporal_load((const vfloat4*)p);
    return make_float4(v.x, v.y, v.z, v.w);
}

// Double-buffered LDS GEMM: C[M][N] = A[M][K] @ W[K][N] + bias[N].
// Tile (RPT*16) x 64, BK=32, 256 threads, RPT x 4 outputs/thread.
// One __syncthreads per K-step; next tile's global loads issued before compute
// so HBM/L2 latency hides under the 512-cycle FMA block.
template<int RPT>
__global__ __launch_bounds__(256) void gemm_db(
    const float* __restrict__ A, const float* __restrict__ W,
    const float* __restrict__ bias, float* __restrict__ C,
    int M, int N, int K)
{
    __shared__ float As[2][RPT * 16][36];
    __shared__ float Bs[2][32][68];
    const int tid = threadIdx.x;
    const int tx = tid & 15;               // col group: n0 + tx*4 .. +3
    const int ty = tid >> 4;               // row group: m0 + ty*RPT .. +RPT-1
    const int n0 = blockIdx.x * 64;
    const int m0 = blockIdx.y * (RPT * 16);

    // staging maps
    const int ar = (RPT == 2) ? (tid >> 3) : (tid >> 4);          // A row
    const int ak = (RPT == 2) ? ((tid & 7) * 4) : ((tid & 15) * 2); // A k-offset
    const int bk = tid >> 4;               // B rows bk, bk+16
    const int bc = (tid & 15) * 4;         // B col offset

    const float* aP = A + (size_t)(m0 + ar) * K + ak;
    const float* wP = W + (size_t)bk * N + n0 + bc;
    const size_t wRow16 = (size_t)16 * N;

    // prologue: stage tile 0
    if (RPT == 2) {
        *(float4*)&As[0][ar][ak] = *(const float4*)aP;
    } else {
        *(float2*)&As[0][ar][ak] = *(const float2*)aP;
    }
    *(float4*)&Bs[0][bk][bc]      = *(const float4*)wP;
    *(float4*)&Bs[0][bk + 16][bc] = *(const float4*)(wP + wRow16);

    float acc[RPT][4];
    #pragma unroll
    for (int r = 0; r < RPT; ++r)
        #pragma unroll
        for (int j = 0; j < 4; ++j) acc[r][j] = 0.f;

    const int nsteps = K >> 5;
    for (int s = 0; s < nsteps; ++s) {
        __syncthreads();
        const int cur = s & 1, nxt = cur ^ 1;

        float4 na4; float2 na2; float4 nb0, nb1;
        const bool pf = (s + 1 < nsteps);
        if (pf) {
            const float* aN = aP + (s + 1) * 32;
            const float* wN = wP + (size_t)(s + 1) * 32 * N;
            if (RPT == 2) na4 = *(const float4*)aN; else na2 = *(const float2*)aN;
            nb0 = *(const float4*)wN;
            nb1 = *(const float4*)(wN + wRow16);
        }

        #pragma unroll
        for (int k = 0; k < 32; k += 2) {
            float2 arow[RPT];
            #pragma unroll
            for (int r = 0; r < RPT; ++r)
                arow[r] = *(const float2*)&As[cur][ty * RPT + r][k];
            const float4 bA = *(const float4*)&Bs[cur][k][tx * 4];
            const float4 bB = *(const float4*)&Bs[cur][k + 1][tx * 4];
            #pragma unroll
            for (int r = 0; r < RPT; ++r) {
                acc[r][0] = fmaf(arow[r].x, bA.x, acc[r][0]);
                acc[r][1] = fmaf(arow[r].x, bA.y, acc[r][1]);
                acc[r][2] = fmaf(arow[r].x, bA.z, acc[r][2]);
                acc[r][3] = fmaf(arow[r].x, bA.w, acc[r][3]);
                acc[r][0] = fmaf(arow[r].y, bB.x, acc[r][0]);
                acc[r][1] = fmaf(arow[r].y, bB.y, acc[r][1]);
                acc[r][2] = fmaf(arow[r].y, bB.z, acc[r][2]);
                acc[r][3] = fmaf(arow[r].y, bB.w, acc[r][3]);
            }
        }

        if (pf) {
            // nxt buffer was last read at step s-1; all threads are past the
            // top-of-step-s barrier, so writing it now is race-free.
            if (RPT == 2) {
                *(float4*)&As[nxt][ar][ak] = na4;
            } else {
                *(float2*)&As[nxt][ar][ak] = na2;
            }
            *(float4*)&Bs[nxt][bk][bc]      = nb0;
            *(float4*)&Bs[nxt][bk + 16][bc] = nb1;
        }
    }

    const float4 bs4 = *(const float4*)&bias[n0 + tx * 4];
    #pragma unroll
    for (int r = 0; r < RPT; ++r) {
        float4 o;
        o.x = acc[r][0] + bs4.x;
        o.y = acc[r][1] + bs4.y;
        o.z = acc[r][2] + bs4.z;
        o.w = acc[r][3] + bs4.w;
        *(float4*)&C[(size_t)(m0 + ty * RPT + r) * N + n0 + tx * 4] = o;
    }
}

// Block = (b, t-pair). 512 threads / 8 waves. Lane = (si in 8 s-rows, dq in 8 d-octets).
__global__ __launch_bounds__(512, 2) void attn_kernel(
    const float* __restrict__ qkv,     // (B*T, 1536): [q|k|v]
    const float* __restrict__ mask,    // (B, T, T, 32, 2) = (..., 64 floats)
    const float* __restrict__ pad,     // (B, T)
    float* __restrict__ o_attn,        // (B*T, 512)
    float* __restrict__ attn_w)        // (B*T, 256)
{
    __shared__ float q_s[2][Ee];       // 4 KB
    __shared__ float sc[2][Hh][Tt];    // 16 KB
    __shared__ float rrs[16];          // reciprocal softmax sums, row = tt*8+h
    const int tid  = threadIdx.x;
    const int lane = tid & 63;
    const int wv   = tid >> 6;         // 0..7
    const int si   = lane >> 3;        // 0..7
    const int dq   = lane & 7;         // 0..7 -> d = dq*8..dq*8+7
    const int b    = blockIdx.x >> 7;
    const int t0   = (blockIdx.x & 127) * 2;

    // stage q rows (t0, t0+1) into LDS: 1024 floats, float2 per thread
    {
        const int e = tid * 2;
        const int t = e >> 9, off = e & 511;
        *(float2*)&q_s[t][off] =
            *(const float2*)&qkv[(size_t)(b * Tt + t0 + t) * E3 + off];
    }
    __syncthreads();

    const float scale = 0.125f;  // 1/sqrt(64)

    // ---- scores: wave handles 4 chunks of 8 s-rows ----
    for (int c = 0; c < 4; ++c) {
        const int s = (wv * 4 + c) * 8 + si;
        const float* mrow0 = mask + ((size_t)((b * Tt + t0) * Tt + s)) * Dd + dq * 8;
        const float* mrow1 = mrow0 + (size_t)Tt * Dd;
        const float4 ma0 = ntload4(mrow0);
        const float4 mb0 = ntload4(mrow0 + 4);
        const float4 ma1 = ntload4(mrow1);
        const float4 mb1 = ntload4(mrow1 + 4);
        const float* krow = qkv + (size_t)(b * Tt + s) * E3 + Ee + dq * 8;
        const float padv = pad[b * Tt + s];
        #pragma unroll
        for (int h = 0; h < Hh; ++h) {
            const float4 ka = *(const float4*)(krow + h * 64);
            const float4 kb = *(const float4*)(krow + h * 64 + 4);
            const float4 qa0 = *(const float4*)&q_s[0][h * 64 + dq * 8];
            const float4 qb0 = *(const float4*)&q_s[0][h * 64 + dq * 8 + 4];
            const float4 qa1 = *(const float4*)&q_s[1][h * 64 + dq * 8];
            const float4 qb1 = *(const float4*)&q_s[1][h * 64 + dq * 8 + 4];
            // t0
            float u0 = qa0.x * ka.x + qa0.y * ka.y;
            float w0 = qa0.y * ka.x - qa0.x * ka.y;
            float u1 = qa0.z * ka.z + qa0.w * ka.w;
            float w1 = qa0.w * ka.z - qa0.z * ka.w;
            float u2 = qb0.x * kb.x + qb0.y * kb.y;
            float w2 = qb0.y * kb.x - qb0.x * kb.y;
            float u3 = qb0.z * kb.z + qb0.w * kb.w;
            float w3 = qb0.w * kb.z - qb0.z * kb.w;
            float v0 = u0 * ma0.x + w0 * ma0.y + u1 * ma0.z + w1 * ma0.w
                     + u2 * mb0.x + w2 * mb0.y + u3 * mb0.z + w3 * mb0.w;
            // t1
            float s0 = qa1.x * ka.x + qa1.y * ka.y;
            float r0 = qa1.y * ka.x - qa1.x * ka.y;
            float s1 = qa1.z * ka.z + qa1.w * ka.w;
            float r1 = qa1.w * ka.z - qa1.z * ka.w;
            float s2 = qb1.x * kb.x + qb1.y * kb.y;
            float r2 = qb1.y * kb.x - qb1.x * kb.y;
            float s3 = qb1.z * kb.z + qb1.w * kb.w;
            float r3 = qb1.w * kb.z - qb1.z * kb.w;
            float v1 = s0 * ma1.x + r0 * ma1.y + s1 * ma1.z + r1 * ma1.w
                     + s2 * mb1.x + r2 * mb1.y + s3 * mb1.z + r3 * mb1.w;
            // reduce over dq (8 lanes)
            v0 += __shfl_xor(v0, 1); v0 += __shfl_xor(v0, 2); v0 += __shfl_xor(v0, 4);
            v1 += __shfl_xor(v1, 1); v1 += __shfl_xor(v1, 2); v1 += __shfl_xor(v1, 4);
            if (dq == 0) {
                sc[0][h][s] = v0 * scale + padv;
                sc[1][h][s] = v1 * scale + padv;
            }
        }
    }
    __syncthreads();

    // ---- softmax: 16 rows (t,h); wave handles rows wv*2, wv*2+1 ----
    #pragma unroll
    for (int r = 0; r < 2; ++r) {
        const int row = wv * 2 + r;
        float* pr = &sc[0][0][0] + row * Tt;
        float4 xv = *(const float4*)&pr[lane * 4];
        float mx = fmaxf(fmaxf(xv.x, xv.y), fmaxf(xv.z, xv.w));
        #pragma unroll
        for (int dlt = 32; dlt >= 1; dlt >>= 1) mx = fmaxf(mx, __shfl_xor(mx, dlt));
        float4 ev;
        ev.x = __expf(xv.x - mx);
        ev.y = __expf(xv.y - mx);
        ev.z = __expf(xv.z - mx);
        ev.w = __expf(xv.w - mx);
        float sum = (ev.x + ev.y) + (ev.z + ev.w);
        #pragma unroll
        for (int dlt = 32; dlt >= 1; dlt >>= 1) sum += __shfl_xor(sum, dlt);
        *(float4*)&pr[lane * 4] = ev;
        if (lane == 0) rrs[row] = 1.0f / sum;
    }
    __syncthreads();

    // ---- attn_weights: thread (tt, s2) ----
    {
        const int tt = tid >> 8, s2 = tid & 255;
        float aw = 0.f;
        #pragma unroll
        for (int h = 0; h < Hh; ++h) aw += sc[tt][h][s2] * rrs[tt * 8 + h];
        attn_w[(size_t)(b * Tt + t0 + tt) * Tt + s2] = aw * 0.125f;
    }

    // ---- PV: thread (h, d), both t rows share v loads ----
    {
        const int h = tid >> 6, d = tid & 63;
        const float r0 = rrs[h], r1 = rrs[8 + h];
        const float* vb = qkv + (size_t)b * Tt * E3 + 2 * Ee + h * 64 + d;
        float o0 = 0.f, o1 = 0.f;
        for (int s2 = 0; s2 < Tt; s2 += 4) {
            const float4 p0 = *(const float4*)&sc[0][h][s2];
            const float4 p1 = *(const float4*)&sc[1][h][s2];
            float vv;
            vv = vb[(size_t)(s2 + 0) * E3]; o0 = fmaf(p0.x, vv, o0); o1 = fmaf(p1.x, vv, o1);
            vv = vb[(size_t)(s2 + 1) * E3]; o0 = fmaf(p0.y, vv, o0); o1 = fmaf(p1.y, vv, o1);
            vv = vb[(size_t)(s2 + 2) * E3]; o0 = fmaf(p0.z, vv, o0); o1 = fmaf(p1.z, vv, o1);
            vv = vb[(size_t)(s2 + 3) * E3]; o0 = fmaf(p0.w, vv, o0); o1 = fmaf(p1.w, vv, o1);
        }
        o_attn[(size_t)(b * Tt + t0) * Ee + tid]     = o0 * r0;
        o_attn[(size_t)(b * Tt + t0 + 1) * Ee + tid] = o1 * r1;
    }
}

extern "C" void kernel_launch(void* const* d_in, const int* in_sizes, int n_in,
                              void* d_out, int out_size, void* d_ws, size_t ws_size,
                              hipStream_t stream) {
    const float* x    = (const float*)d_in[0];
    const float* mask = (const float*)d_in[1];
    const float* pad  = (const float*)d_in[2];
    const float* Wqkv = (const float*)d_in[3];
    const float* bqkv = (const float*)d_in[4];
    const float* Wo   = (const float*)d_in[5];
    const float* bo   = (const float*)d_in[6];

    float* out    = (float*)d_out;               // o (B*T*E) then attn_w (B*T*T)
    float* qkv    = (float*)d_ws;                // B*T*3E = 786432 floats
    float* o_attn = qkv + (size_t)Bb * Tt * E3;  // B*T*E  = 262144 floats

    // qkv = x @ Wqkv + bqkv   (32x64 tiles: grid 24 x 16 = 384 blocks)
    gemm_db<2><<<dim3(E3 / 64, (Bb * Tt) / 32), 256, 0, stream>>>(
        x, Wqkv, bqkv, qkv, Bb * Tt, E3, Ee);

    // fused rotary scores + softmax + attn_weights + PV  (256 blocks x 512 thr)
    attn_kernel<<<dim3(Bb * (Tt / 2)), 512, 0, stream>>>(
        qkv, mask, pad, o_attn, out + (size_t)Bb * Tt * Ee);

    // out = o_attn @ Wo + bo  (16x64 tiles: grid 8 x 32 = 256 blocks)
    gemm_db<1><<<dim3(Ee / 64, (Bb * Tt) / 16), 256, 0, stream>>>(
        o_attn, Wo, bo, out, Bb * Tt, Ee, Ee);
}